// Round 4
// baseline (153.081 us; speedup 1.0000x reference)
//
#include <hip/hip_runtime.h>
#include <math.h>
#include <stdint.h>

// EKF batch step, N independent 5-state filters.
// Exploits A rows 3,4 == 0 => P_ has zero cross blocks, S diagonal,
// K has only 2 nonzeros.
//
// R3 (resubmit; previous round was an infra failure, not a kernel verdict):
// async global->LDS staging (global_load_lds) for full blocks.
// Dynamic-trip-count staging loops serialized at 1 outstanding load/wave
// (R2 post-mortem: ~2.4 TB/s == in-flight-bytes-limited). Now each wave
// issues 9 async LDS-DMA loads (7.5 KB in flight) with one vmcnt(0) drain
// at the barrier; store phase statically unrolled so ds_read/store pipeline.

#define BLK 64

__device__ __forceinline__ void gload_lds16(const void* g, void* l) {
    __builtin_amdgcn_global_load_lds(
        (const __attribute__((address_space(1))) void*)g,
        (__attribute__((address_space(3))) void*)l, 16, 0, 0);
}
__device__ __forceinline__ void gload_lds4(const void* g, void* l) {
    __builtin_amdgcn_global_load_lds(
        (const __attribute__((address_space(1))) void*)g,
        (__attribute__((address_space(3))) void*)l, 4, 0, 0);
}

__global__ __launch_bounds__(BLK) void ekf_kernel(
    const float* __restrict__ xg,     // N*5
    const float* __restrict__ Pg,     // N*25
    const float* __restrict__ ag,     // N*2
    const float* __restrict__ Yg,     // 2*N
    const float* __restrict__ n1,     // 5
    const float* __restrict__ n2s,    // 2
    const float* __restrict__ n2k,    // 2
    const float* __restrict__ gains,  // 2
    const float* __restrict__ og,     // 2
    float* __restrict__ out,          // x_new[5N] | P_new[25N] | K[10N]
    int N)
{
    // LDS layout: [P: 64*25][x: 64*5][K: 64*10] = 2560 floats = 10.25 KiB
    __shared__ float lds[BLK * 25 + BLK * 5 + BLK * 10];
    float* ldsP = lds;
    float* ldsX = lds + BLK * 25;
    float* ldsK = lds + BLK * 25 + BLK * 5;

    const int tid  = threadIdx.x;
    const int base = blockIdx.x * BLK;
    const int valid = min(BLK, N - base);
    if (valid <= 0) return;
    const bool full = (valid == BLK);

    // ---- Phase 1: stage P and x into LDS ----
    if (full) {
        // P tile: 64*25*4 = 6400 B = 6*1024 + 256. x tile: 1280 B = 1024 + 256.
        // global src is per-lane; LDS dest is wave-uniform base (+ lane*size by HW).
        const char* gp = (const char*)(Pg + (size_t)base * 25);
        char* lp = (char*)ldsP;
        #pragma unroll
        for (int j = 0; j < 6; ++j)
            gload_lds16(gp + j * 1024 + tid * 16, lp + j * 1024);
        gload_lds4(gp + 6144 + tid * 4, lp + 6144);

        const char* gx = (const char*)(xg + (size_t)base * 5);
        char* lx = (char*)ldsX;
        gload_lds16(gx + tid * 16, lx);
        gload_lds4(gx + 1024 + tid * 4, lx + 1024);

        asm volatile("s_waitcnt vmcnt(0)" ::: "memory");
    } else {
        for (int k = tid; k < valid * 25; k += BLK) ldsP[k] = Pg[(size_t)base * 25 + k];
        for (int k = tid; k < valid * 5;  k += BLK) ldsX[k] = xg[(size_t)base * 5 + k];
    }
    __syncthreads();

    // ---- Phase 2: per-thread compute ----
    if (tid < valid) {
        const int i = base + tid;
        const float dt = 0.1f;
        const float fPI = 3.14159265358979323846f;
        const float f2PI = 6.28318530717958647692f;

        float2 ai = ((const float2*)ag)[i];           // coalesced 8B load
        float vel    = gains[0] * ai.x;
        float angvel = gains[1] * ai.y;

        float x0 = ldsX[tid * 5 + 0];
        float x1 = ldsX[tid * 5 + 1];
        float x2 = ldsX[tid * 5 + 2];

        // range_angle: numpy mod semantics = fmodf + sign fix
        float ar = x2 + angvel * dt + fPI;
        float w = fmodf(ar, f2PI);
        if (w < 0.0f) w += f2PI;
        float ang = w - fPI;

        float s, c;
        sincosf(ang, &s, &c);

        float px = fminf(fmaxf(x0 + vel * c * dt, -1.0f), 1.0f);
        float py = fminf(fmaxf(x1 + vel * s * dt, -1.0f), 1.0f);

        float m0 = -vel * s * dt;   // A[0][2]
        float m1 =  vel * c * dt;   // A[1][2]

        // P top-left 3x3
        float p00 = ldsP[tid*25 + 0],  p01 = ldsP[tid*25 + 1],  p02 = ldsP[tid*25 + 2];
        float p10 = ldsP[tid*25 + 5],  p11 = ldsP[tid*25 + 6],  p12 = ldsP[tid*25 + 7];
        float p20 = ldsP[tid*25 + 10], p21 = ldsP[tid*25 + 11], p22 = ldsP[tid*25 + 12];

        // B = Atop * P33 (rows 0,1 add m*row2)
        float b00 = p00 + m0 * p20, b01 = p01 + m0 * p21, b02 = p02 + m0 * p22;
        float b10 = p10 + m1 * p20, b11 = p11 + m1 * p21, b12 = p12 + m1 * p22;
        // T = B * Atopᵀ (cols 0,1 add m*col2)
        float t00 = b00 + m0 * b02, t01 = b01 + m1 * b02, t02 = b02;
        float t10 = b10 + m0 * b12, t11 = b11 + m1 * b12, t12 = b12;
        float t20 = p20 + m0 * p22, t21 = p21 + m1 * p22, t22 = p22;

        float q0 = expf(2.0f * n1[0]);
        float q1 = expf(2.0f * n1[1]);
        float q2 = expf(2.0f * n1[2]);
        float q3 = expf(2.0f * n1[3]);
        float q4 = expf(2.0f * n1[4]);

        t00 += q0; t11 += q1; t22 += q2;

        // symmetrize + EPS
        const float EPS_ = 1e-6f;
        float s01 = 0.5f * (t01 + t10);
        float s02 = 0.5f * (t02 + t20);
        float s12 = 0.5f * (t12 + t21);
        t00 += EPS_; t11 += EPS_; t22 += EPS_;

        float og0 = og[0], og1 = og[1];
        float e2s0 = expf(2.0f * n2s[0]), e2s1 = expf(2.0f * n2s[1]);
        float e2k0 = expf(2.0f * n2k[0]), e2k1 = expf(2.0f * n2k[1]);

        float S00 = q3 * og0 * og0 + vel * vel * e2k0 + e2s0;
        float S11 = q4 * og1 * og1 + angvel * angvel * e2k1 + e2s1;

        float K30 = q3 * og0 / S00;
        float K41 = q4 * og1 / S11;

        float y0 = Yg[i], y1 = Yg[N + i];      // coalesced
        float err0 = y0 - og0 * vel;
        float err1 = y1 - og1 * angvel;

        float xn3 = vel    + K30 * err0;
        float xn4 = angvel + K41 * err1;

        float g3 = 1.0f - K30 * og0;
        float g4 = 1.0f - K41 * og1;
        float Pn33 = g3 * q3 + EPS_;
        float Pn44 = g4 * q4 + EPS_;

        // write x_new
        ldsX[tid*5 + 0] = px;
        ldsX[tid*5 + 1] = py;
        ldsX[tid*5 + 2] = ang;
        ldsX[tid*5 + 3] = xn3;
        ldsX[tid*5 + 4] = xn4;

        // write P_new (row-major 5x5)
        float* pp = ldsP + tid * 25;
        pp[0]  = t00;  pp[1]  = s01;  pp[2]  = s02;  pp[3]  = 0.0f; pp[4]  = 0.0f;
        pp[5]  = s01;  pp[6]  = t11;  pp[7]  = s12;  pp[8]  = 0.0f; pp[9]  = 0.0f;
        pp[10] = s02;  pp[11] = s12;  pp[12] = t22;  pp[13] = 0.0f; pp[14] = 0.0f;
        pp[15] = 0.0f; pp[16] = 0.0f; pp[17] = 0.0f; pp[18] = Pn33; pp[19] = 0.0f;
        pp[20] = 0.0f; pp[21] = 0.0f; pp[22] = 0.0f; pp[23] = 0.0f; pp[24] = Pn44;

        // write K (5x2)
        float* kk = ldsK + tid * 10;
        kk[0] = 0.0f; kk[1] = 0.0f; kk[2] = 0.0f; kk[3] = 0.0f;
        kk[4] = 0.0f; kk[5] = 0.0f;
        kk[6] = K30;  kk[7] = 0.0f;
        kk[8] = 0.0f; kk[9] = K41;
    }
    __syncthreads();

    // ---- Phase 3: coalesced store of x_new | P_new | K ----
    float* gx = out + (size_t)base * 5;
    float* gp = out + (size_t)5 * N + (size_t)base * 25;
    float* gk = out + (size_t)30 * N + (size_t)base * 10;

    if (full) {
        // Static trip counts -> compiler issues all ds_reads, pipelines stores.
        float4* gx4 = (float4*)gx;  const float4* lx4 = (const float4*)ldsX;
        float4* gp4 = (float4*)gp;  const float4* lp4 = (const float4*)ldsP;
        float4* gk4 = (float4*)gk;  const float4* lk4 = (const float4*)ldsK;

        // x: 80 float4 = 64 + 16
        gx4[tid] = lx4[tid];
        if (tid < 16) gx4[64 + tid] = lx4[64 + tid];
        // P: 400 float4 = 6*64 + 16
        #pragma unroll
        for (int j = 0; j < 6; ++j) gp4[j * 64 + tid] = lp4[j * 64 + tid];
        if (tid < 16) gp4[384 + tid] = lp4[384 + tid];
        // K: 160 float4 = 2*64 + 32
        #pragma unroll
        for (int j = 0; j < 2; ++j) gk4[j * 64 + tid] = lk4[j * 64 + tid];
        if (tid < 32) gk4[128 + tid] = lk4[128 + tid];
    } else {
        for (int k = tid; k < valid * 5;  k += BLK) gx[k] = ldsX[k];
        for (int k = tid; k < valid * 25; k += BLK) gp[k] = ldsP[k];
        for (int k = tid; k < valid * 10; k += BLK) gk[k] = ldsK[k];
    }
}

extern "C" void kernel_launch(void* const* d_in, const int* in_sizes, int n_in,
                              void* d_out, int out_size, void* d_ws, size_t ws_size,
                              hipStream_t stream) {
    const float* x     = (const float*)d_in[0];
    const float* P     = (const float*)d_in[1];
    const float* a     = (const float*)d_in[2];
    const float* Y     = (const float*)d_in[3];
    const float* n1    = (const float*)d_in[4];
    const float* n2s   = (const float*)d_in[5];
    const float* n2k   = (const float*)d_in[6];
    const float* gains = (const float*)d_in[7];
    const float* og    = (const float*)d_in[8];
    const int N = in_sizes[0] / 5;
    const int grid = (N + BLK - 1) / BLK;
    ekf_kernel<<<grid, BLK, 0, stream>>>(x, P, a, Y, n1, n2s, n2k, gains, og,
                                         (float*)d_out, N);
}

// Round 6
// 150.072 us; speedup vs baseline: 1.0200x; 1.0200x over previous
//
#include <hip/hip_runtime.h>
#include <math.h>
#include <stdint.h>

// EKF batch step, N independent 5-state filters.
// Exploits A rows 3,4 == 0 => P_ has zero cross blocks, S diagonal,
// K has only 2 nonzeros.
//
// R5 (resubmit; R5 round was a GPU-acquisition timeout, not a kernel verdict):
// persistent double-buffered pipeline.
//  - G=1280 one-wave blocks (5/CU via 27.6KB LDS), grid-stride over 64-item tiles.
//  - Per tile: 13 async global_load_lds (P,x,a,Y -> LDS), counted
//    s_waitcnt vmcnt(N) so prefetch loads + stores stay in flight across
//    iterations (load latency hidden under previous tile's compute+store).
//  - Uniform expf/gains hoisted out of the item loop; constant-zero output
//    slots written to the out-staging LDS once.
//  - Kills the R4 suspects: 7813-block dispatch-rate and per-block phase
//    serialization (cold-start latency per tile).

#define BLK 64
#define TILE_F 2176   // floats per in-buffer: P 1600 | x 320 | a 128 | Y 128
#define OFF_X  1600
#define OFF_A  1920
#define OFF_Y  2048
#define OB_X   0      // out-staging: x 320 | P 1600 | K 640 = 2560 floats
#define OB_P   320
#define OB_K   1920

__device__ __forceinline__ void gload_lds16(const void* g, void* l) {
    __builtin_amdgcn_global_load_lds(
        (const __attribute__((address_space(1))) void*)g,
        (__attribute__((address_space(3))) void*)l, 16, 0, 0);
}
__device__ __forceinline__ void gload_lds4(const void* g, void* l) {
    __builtin_amdgcn_global_load_lds(
        (const __attribute__((address_space(1))) void*)g,
        (__attribute__((address_space(3))) void*)l, 4, 0, 0);
}

// 13 vmem instructions, 8704 B. LDS dest is wave-uniform base (+lane*size by HW).
__device__ __forceinline__ void stage_tile(const float* Pg, const float* xg,
                                           const float* ag, const float* Yg,
                                           int N, int base, float* buf, int tid) {
    const char* gp = (const char*)(Pg + (size_t)base * 25);
    char* lp = (char*)buf;
    #pragma unroll
    for (int j = 0; j < 6; ++j)
        gload_lds16(gp + j * 1024 + tid * 16, lp + j * 1024);   // 6400 B
    gload_lds4(gp + 6144 + tid * 4, lp + 6144);
    const char* gx = (const char*)(xg + (size_t)base * 5);
    gload_lds16(gx + tid * 16, lp + 6400);                       // 1280 B
    gload_lds4(gx + 1024 + tid * 4, lp + 6400 + 1024);
    const char* ga = (const char*)(ag + (size_t)base * 2);
    gload_lds4(ga + tid * 4,       lp + 7680);                   // 512 B
    gload_lds4(ga + 256 + tid * 4, lp + 7680 + 256);
    gload_lds4((const char*)(Yg + base)     + tid * 4, lp + 8192); // 512 B
    gload_lds4((const char*)(Yg + N + base) + tid * 4, lp + 8192 + 256);
}

struct EkfOut {
    float px, py, ang, xn3, xn4;
    float t00, s01, s02, t11, s12, t22, Pn33, Pn44;
    float K30, K41;
};

__device__ __forceinline__ EkfOut ekf_math(
    float x0, float x1, float x2, float a0, float a1, float y0, float y1,
    float p00, float p01, float p02, float p10, float p11, float p12,
    float p20, float p21, float p22,
    float g0, float g1, float og0, float og1,
    float q0, float q1, float q2, float q3, float q4,
    float e2s0, float e2s1, float e2k0, float e2k1)
{
    const float dt = 0.1f;
    const float fPI  = 3.14159265358979323846f;
    const float f2PI = 6.28318530717958647692f;
    const float EPS_ = 1e-6f;

    float vel = g0 * a0, angvel = g1 * a1;

    float ar = x2 + angvel * dt + fPI;
    float w = fmodf(ar, f2PI);
    if (w < 0.0f) w += f2PI;
    float ang = w - fPI;

    float s, c;
    sincosf(ang, &s, &c);

    EkfOut o;
    o.px = fminf(fmaxf(x0 + vel * c * dt, -1.0f), 1.0f);
    o.py = fminf(fmaxf(x1 + vel * s * dt, -1.0f), 1.0f);
    o.ang = ang;

    float m0 = -vel * s * dt, m1 = vel * c * dt;

    float b00 = p00 + m0 * p20, b01 = p01 + m0 * p21, b02 = p02 + m0 * p22;
    float b10 = p10 + m1 * p20, b11 = p11 + m1 * p21, b12 = p12 + m1 * p22;
    float t00 = b00 + m0 * b02, t01 = b01 + m1 * b02;
    float t10 = b10 + m0 * b12, t11 = b11 + m1 * b12;
    float t20 = p20 + m0 * p22, t21 = p21 + m1 * p22, t22 = p22;
    float t02 = b02, t12 = b12;

    t00 += q0; t11 += q1; t22 += q2;
    o.s01 = 0.5f * (t01 + t10);
    o.s02 = 0.5f * (t02 + t20);
    o.s12 = 0.5f * (t12 + t21);
    o.t00 = t00 + EPS_; o.t11 = t11 + EPS_; o.t22 = t22 + EPS_;

    float S00 = q3 * og0 * og0 + vel * vel * e2k0 + e2s0;
    float S11 = q4 * og1 * og1 + angvel * angvel * e2k1 + e2s1;
    o.K30 = q3 * og0 / S00;
    o.K41 = q4 * og1 / S11;

    o.xn3 = vel    + o.K30 * (y0 - og0 * vel);
    o.xn4 = angvel + o.K41 * (y1 - og1 * angvel);
    o.Pn33 = (1.0f - o.K30 * og0) * q3 + EPS_;
    o.Pn44 = (1.0f - o.K41 * og1) * q4 + EPS_;
    return o;
}

__global__ __launch_bounds__(BLK) void ekf_kernel(
    const float* __restrict__ xg, const float* __restrict__ Pg,
    const float* __restrict__ ag, const float* __restrict__ Yg,
    const float* __restrict__ n1, const float* __restrict__ n2s,
    const float* __restrict__ n2k, const float* __restrict__ gains,
    const float* __restrict__ og, float* __restrict__ out, int N)
{
    __shared__ float lds[2 * TILE_F + 2560];   // 27,648 B -> 5 blocks/CU
    float* bufA = lds;
    float* bufB = lds + TILE_F;
    float* obuf = lds + 2 * TILE_F;

    const int tid = threadIdx.x;
    const int tiles = (N + BLK - 1) / BLK;
    const int G = gridDim.x, b = blockIdx.x;
    const int q = tiles / G, r = tiles % G;
    const int t0 = b * q + min(b, r);
    const int myTiles = q + (b < r ? 1 : 0);
    if (myTiles <= 0) return;

    // Uniform scalars + transcendentals, once per block.
    const float g0 = gains[0], g1 = gains[1];
    const float og0 = og[0], og1 = og[1];
    const float q0 = expf(2.f * n1[0]), q1 = expf(2.f * n1[1]),
                q2 = expf(2.f * n1[2]), q3 = expf(2.f * n1[3]),
                q4 = expf(2.f * n1[4]);
    const float e2s0 = expf(2.f * n2s[0]), e2s1 = expf(2.f * n2s[1]);
    const float e2k0 = expf(2.f * n2k[0]), e2k1 = expf(2.f * n2k[1]);

    // Constant-zero output slots: written once, persist across iterations.
    {
        float* pp = obuf + OB_P + tid * 25;
        pp[3] = 0.f; pp[4] = 0.f; pp[8] = 0.f; pp[9] = 0.f;
        pp[13] = 0.f; pp[14] = 0.f;
        pp[15] = 0.f; pp[16] = 0.f; pp[17] = 0.f; pp[19] = 0.f;
        pp[20] = 0.f; pp[21] = 0.f; pp[22] = 0.f; pp[23] = 0.f;
        float* kk = obuf + OB_K + tid * 10;
        kk[0] = 0.f; kk[1] = 0.f; kk[2] = 0.f; kk[3] = 0.f;
        kk[4] = 0.f; kk[5] = 0.f; kk[7] = 0.f; kk[8] = 0.f;
    }

    // Prologue prefetch of first tile (if full).
    {
        int base0 = t0 * BLK;
        if (base0 + BLK <= N) stage_tile(Pg, xg, ag, Yg, N, base0, bufA, tid);
    }
    float* cur = bufA;
    float* nxt = bufB;

    for (int k = 0; k < myTiles; ++k) {
        const int t = t0 + k;
        const int base = t * BLK;
        const bool fullT = (base + BLK <= N);

        bool issued = false;
        if (k + 1 < myTiles) {
            int nb = (t + 1) * BLK;
            if (nb + BLK <= N) { stage_tile(Pg, xg, ag, Yg, N, nb, nxt, tid); issued = true; }
        }

        if (fullT) {
            // Wait for THIS tile's 13 loads only; leave prefetch (13) and
            // prior stores (12) in flight. FIFO invariant: max 50 outstanding.
            if (k == 0) { if (issued) asm volatile("s_waitcnt vmcnt(13)" ::: "memory");
                          else        asm volatile("s_waitcnt vmcnt(0)"  ::: "memory"); }
            else        { if (issued) asm volatile("s_waitcnt vmcnt(25)" ::: "memory");
                          else        asm volatile("s_waitcnt vmcnt(12)" ::: "memory"); }

            // Compute from cur -> obuf
            float x0 = cur[OFF_X + tid * 5 + 0];
            float x1 = cur[OFF_X + tid * 5 + 1];
            float x2 = cur[OFF_X + tid * 5 + 2];
            float2 av = *(const float2*)&cur[OFF_A + tid * 2];
            float y0 = cur[OFF_Y + tid];
            float y1 = cur[OFF_Y + 64 + tid];
            const float* pr = cur + tid * 25;
            EkfOut o = ekf_math(x0, x1, x2, av.x, av.y, y0, y1,
                                pr[0], pr[1], pr[2], pr[5], pr[6], pr[7],
                                pr[10], pr[11], pr[12],
                                g0, g1, og0, og1, q0, q1, q2, q3, q4,
                                e2s0, e2s1, e2k0, e2k1);

            float* xx = obuf + OB_X + tid * 5;
            xx[0] = o.px; xx[1] = o.py; xx[2] = o.ang; xx[3] = o.xn3; xx[4] = o.xn4;
            float* pp = obuf + OB_P + tid * 25;
            pp[0] = o.t00; pp[1] = o.s01; pp[2] = o.s02;
            pp[5] = o.s01; pp[6] = o.t11; pp[7] = o.s12;
            pp[10] = o.s02; pp[11] = o.s12; pp[12] = o.t22;
            pp[18] = o.Pn33; pp[24] = o.Pn44;
            float* kk = obuf + OB_K + tid * 10;
            kk[6] = o.K30; kk[9] = o.K41;

            // Store obuf -> global: 12 dwordx4 instructions (x:2, P:7, K:3).
            float4* gx4 = (float4*)(out + (size_t)base * 5);
            float4* gp4 = (float4*)(out + (size_t)5 * N + (size_t)base * 25);
            float4* gk4 = (float4*)(out + (size_t)30 * N + (size_t)base * 10);
            const float4* lx4 = (const float4*)(obuf + OB_X);
            const float4* lp4 = (const float4*)(obuf + OB_P);
            const float4* lk4 = (const float4*)(obuf + OB_K);
            gx4[tid] = lx4[tid];
            if (tid < 16) gx4[64 + tid] = lx4[64 + tid];
            #pragma unroll
            for (int j = 0; j < 6; ++j) gp4[j * 64 + tid] = lp4[j * 64 + tid];
            if (tid < 16) gp4[384 + tid] = lp4[384 + tid];
            #pragma unroll
            for (int j = 0; j < 2; ++j) gk4[j * 64 + tid] = lk4[j * 64 + tid];
            if (tid < 32) gk4[128 + tid] = lk4[128 + tid];
        } else {
            // Tail tile (only the global last, valid = N - base < 64):
            // direct guarded per-thread path, no LDS involvement.
            const int i = base + tid;
            if (i < N) {
                const float* pr = Pg + (size_t)i * 25;
                EkfOut o = ekf_math(xg[i * 5 + 0], xg[i * 5 + 1], xg[i * 5 + 2],
                                    ag[i * 2 + 0], ag[i * 2 + 1],
                                    Yg[i], Yg[N + i],
                                    pr[0], pr[1], pr[2], pr[5], pr[6], pr[7],
                                    pr[10], pr[11], pr[12],
                                    g0, g1, og0, og1, q0, q1, q2, q3, q4,
                                    e2s0, e2s1, e2k0, e2k1);
                float* gx = out + (size_t)i * 5;
                gx[0] = o.px; gx[1] = o.py; gx[2] = o.ang; gx[3] = o.xn3; gx[4] = o.xn4;
                float* gp = out + (size_t)5 * N + (size_t)i * 25;
                gp[0] = o.t00; gp[1] = o.s01; gp[2] = o.s02; gp[3] = 0.f; gp[4] = 0.f;
                gp[5] = o.s01; gp[6] = o.t11; gp[7] = o.s12; gp[8] = 0.f; gp[9] = 0.f;
                gp[10] = o.s02; gp[11] = o.s12; gp[12] = o.t22; gp[13] = 0.f; gp[14] = 0.f;
                gp[15] = 0.f; gp[16] = 0.f; gp[17] = 0.f; gp[18] = o.Pn33; gp[19] = 0.f;
                gp[20] = 0.f; gp[21] = 0.f; gp[22] = 0.f; gp[23] = 0.f; gp[24] = o.Pn44;
                float* gk = out + (size_t)30 * N + (size_t)i * 10;
                gk[0] = 0.f; gk[1] = 0.f; gk[2] = 0.f; gk[3] = 0.f; gk[4] = 0.f;
                gk[5] = 0.f; gk[6] = o.K30; gk[7] = 0.f; gk[8] = 0.f; gk[9] = o.K41;
            }
        }

        float* tmp = cur; cur = nxt; nxt = tmp;
    }
}

extern "C" void kernel_launch(void* const* d_in, const int* in_sizes, int n_in,
                              void* d_out, int out_size, void* d_ws, size_t ws_size,
                              hipStream_t stream) {
    const float* x     = (const float*)d_in[0];
    const float* P     = (const float*)d_in[1];
    const float* a     = (const float*)d_in[2];
    const float* Y     = (const float*)d_in[3];
    const float* n1    = (const float*)d_in[4];
    const float* n2s   = (const float*)d_in[5];
    const float* n2k   = (const float*)d_in[6];
    const float* gains = (const float*)d_in[7];
    const float* og    = (const float*)d_in[8];
    const int N = in_sizes[0] / 5;
    const int tiles = (N + BLK - 1) / BLK;
    int G = 1280;                    // 5 blocks/CU x 256 CUs (LDS-exact residency)
    if (G > tiles) G = tiles;
    ekf_kernel<<<G, BLK, 0, stream>>>(x, P, a, Y, n1, n2s, n2k, gains, og,
                                      (float*)d_out, N);
}

// Round 7
// 146.489 us; speedup vs baseline: 1.0450x; 1.0245x over previous
//
#include <hip/hip_runtime.h>
#include <math.h>
#include <stdint.h>

// EKF batch step, N independent 5-state filters.
// Exploits A rows 3,4 == 0 => P_ has zero cross blocks, S diagonal,
// K has only 2 nonzeros.
//
// R7: register-prefetch persistent kernel, NO LDS on the load path.
// Calibrated graded-time (OH=102us from R1/R2) shows every global_load_lds
// variant pinned at 47-51us: the compiler's conservative vmcnt(0)-before-
// ds_read drains the prefetch every tile. Ordinary global->VGPR loads get
// counted vmcnt(N) waits from the compiler => native pipelining.
// Only the 3x3 P block (36B of 100B) is loaded. LDS used solely for the
// output transpose (obuf); single-wave blocks => zero barriers.

#define BLK 64
#define OB_X 0      // obuf: x 320 | P 1600 | K 640 floats = 10.25 KiB
#define OB_P 320
#define OB_K 1920

struct F3 { float a, b, c; };   // 4B-aligned 12B load -> global_load_dwordx3

struct TR {
    float p00,p01,p02,p10,p11,p12,p20,p21,p22;
    float x0,x1,x2,a0,a1,y0,y1;
};

__device__ __forceinline__ void load_tile(TR& r,
    const float* __restrict__ Pg, const float* __restrict__ xg,
    const float* __restrict__ ag, const float* __restrict__ Yg,
    int N, int i) {
    const float* pb = Pg + (size_t)i * 25;
    F3 r0 = *(const F3*)(pb);        // floats 0..2
    F3 r1 = *(const F3*)(pb + 5);    // floats 5..7
    F3 r2 = *(const F3*)(pb + 10);   // floats 10..12
    F3 xx = *(const F3*)(xg + (size_t)i * 5);
    float2 av = *(const float2*)(ag + (size_t)i * 2);
    r.p00 = r0.a; r.p01 = r0.b; r.p02 = r0.c;
    r.p10 = r1.a; r.p11 = r1.b; r.p12 = r1.c;
    r.p20 = r2.a; r.p21 = r2.b; r.p22 = r2.c;
    r.x0 = xx.a; r.x1 = xx.b; r.x2 = xx.c;
    r.a0 = av.x; r.a1 = av.y;
    r.y0 = Yg[i]; r.y1 = Yg[N + i];
}

struct EkfOut {
    float px, py, ang, xn3, xn4;
    float t00, s01, s02, t11, s12, t22, Pn33, Pn44;
    float K30, K41;
};

__device__ __forceinline__ EkfOut ekf_math(
    float x0, float x1, float x2, float a0, float a1, float y0, float y1,
    float p00, float p01, float p02, float p10, float p11, float p12,
    float p20, float p21, float p22,
    float g0, float g1, float og0, float og1,
    float q0, float q1, float q2, float q3, float q4,
    float e2s0, float e2s1, float e2k0, float e2k1)
{
    const float dt = 0.1f;
    const float fPI  = 3.14159265358979323846f;
    const float f2PI = 6.28318530717958647692f;
    const float EPS_ = 1e-6f;

    float vel = g0 * a0, angvel = g1 * a1;

    float ar = x2 + angvel * dt + fPI;
    float w = fmodf(ar, f2PI);
    if (w < 0.0f) w += f2PI;
    float ang = w - fPI;

    float s, c;
    sincosf(ang, &s, &c);

    EkfOut o;
    o.px = fminf(fmaxf(x0 + vel * c * dt, -1.0f), 1.0f);
    o.py = fminf(fmaxf(x1 + vel * s * dt, -1.0f), 1.0f);
    o.ang = ang;

    float m0 = -vel * s * dt, m1 = vel * c * dt;

    float b00 = p00 + m0 * p20, b01 = p01 + m0 * p21, b02 = p02 + m0 * p22;
    float b10 = p10 + m1 * p20, b11 = p11 + m1 * p21, b12 = p12 + m1 * p22;
    float t00 = b00 + m0 * b02, t01 = b01 + m1 * b02;
    float t10 = b10 + m0 * b12, t11 = b11 + m1 * b12;
    float t20 = p20 + m0 * p22, t21 = p21 + m1 * p22, t22 = p22;
    float t02 = b02, t12 = b12;

    t00 += q0; t11 += q1; t22 += q2;
    o.s01 = 0.5f * (t01 + t10);
    o.s02 = 0.5f * (t02 + t20);
    o.s12 = 0.5f * (t12 + t21);
    o.t00 = t00 + EPS_; o.t11 = t11 + EPS_; o.t22 = t22 + EPS_;

    float S00 = q3 * og0 * og0 + vel * vel * e2k0 + e2s0;
    float S11 = q4 * og1 * og1 + angvel * angvel * e2k1 + e2s1;
    o.K30 = q3 * og0 / S00;
    o.K41 = q4 * og1 / S11;

    o.xn3 = vel    + o.K30 * (y0 - og0 * vel);
    o.xn4 = angvel + o.K41 * (y1 - og1 * angvel);
    o.Pn33 = (1.0f - o.K30 * og0) * q3 + EPS_;
    o.Pn44 = (1.0f - o.K41 * og1) * q4 + EPS_;
    return o;
}

__global__ __launch_bounds__(BLK) void ekf_kernel(
    const float* __restrict__ xg, const float* __restrict__ Pg,
    const float* __restrict__ ag, const float* __restrict__ Yg,
    const float* __restrict__ n1, const float* __restrict__ n2s,
    const float* __restrict__ n2k, const float* __restrict__ gains,
    const float* __restrict__ og, float* __restrict__ out, int N)
{
    __shared__ float obuf[2560];   // 10.25 KiB, output transpose only

    const int tid = threadIdx.x;
    const int tiles = (N + BLK - 1) / BLK;
    const int G = gridDim.x, blk = blockIdx.x;
    const int qt = tiles / G, rt = tiles % G;
    const int t0 = blk * qt + min(blk, rt);
    const int myTiles = qt + (blk < rt ? 1 : 0);
    if (myTiles <= 0) return;

    // Uniform scalars + transcendentals, once per wave.
    const float g0 = gains[0], g1 = gains[1];
    const float og0 = og[0], og1 = og[1];
    const float q0 = expf(2.f * n1[0]), q1 = expf(2.f * n1[1]),
                q2 = expf(2.f * n1[2]), q3 = expf(2.f * n1[3]),
                q4 = expf(2.f * n1[4]);
    const float e2s0 = expf(2.f * n2s[0]), e2s1 = expf(2.f * n2s[1]);
    const float e2k0 = expf(2.f * n2k[0]), e2k1 = expf(2.f * n2k[1]);

    // Constant-zero output slots: written once, persist across iterations.
    {
        float* pp = obuf + OB_P + tid * 25;
        pp[3] = 0.f; pp[4] = 0.f; pp[8] = 0.f; pp[9] = 0.f;
        pp[13] = 0.f; pp[14] = 0.f;
        pp[15] = 0.f; pp[16] = 0.f; pp[17] = 0.f; pp[19] = 0.f;
        pp[20] = 0.f; pp[21] = 0.f; pp[22] = 0.f; pp[23] = 0.f;
        float* kk = obuf + OB_K + tid * 10;
        kk[0] = 0.f; kk[1] = 0.f; kk[2] = 0.f; kk[3] = 0.f;
        kk[4] = 0.f; kk[5] = 0.f; kk[7] = 0.f; kk[8] = 0.f;
    }

    TR A, B;
    {   // prologue prefetch of first tile (if full)
        int i0 = t0 * BLK;
        if (i0 + BLK <= N) load_tile(A, Pg, xg, ag, Yg, N, i0 + tid);
    }

    int k = 0;
    auto process = [&](TR& cur, TR& nxt) {
        const int base = (t0 + k) * BLK;
        const int i = base + tid;
        if (base + BLK <= N) {
            // Prefetch tile k+1 (issue only; compiler places counted vmcnt
            // before its first USE next iteration -> true pipelining).
            if (k + 1 < myTiles) {
                int nb = base + BLK;
                if (nb + BLK <= N) load_tile(nxt, Pg, xg, ag, Yg, N, nb + tid);
            }

            EkfOut o = ekf_math(cur.x0, cur.x1, cur.x2, cur.a0, cur.a1,
                                cur.y0, cur.y1,
                                cur.p00, cur.p01, cur.p02,
                                cur.p10, cur.p11, cur.p12,
                                cur.p20, cur.p21, cur.p22,
                                g0, g1, og0, og1, q0, q1, q2, q3, q4,
                                e2s0, e2s1, e2k0, e2k1);

            // Transpose through obuf (same wave: lgkmcnt ordering only,
            // no barriers, no LDS-DMA conservative drains).
            float* xx = obuf + OB_X + tid * 5;
            xx[0] = o.px; xx[1] = o.py; xx[2] = o.ang; xx[3] = o.xn3; xx[4] = o.xn4;
            float* pp = obuf + OB_P + tid * 25;
            pp[0] = o.t00; pp[1] = o.s01; pp[2] = o.s02;
            pp[5] = o.s01; pp[6] = o.t11; pp[7] = o.s12;
            pp[10] = o.s02; pp[11] = o.s12; pp[12] = o.t22;
            pp[18] = o.Pn33; pp[24] = o.Pn44;
            float* kk = obuf + OB_K + tid * 10;
            kk[6] = o.K30; kk[9] = o.K41;

            // Coalesced stores: 12 dwordx4 per wave.
            float4* gx4 = (float4*)(out + (size_t)base * 5);
            float4* gp4 = (float4*)(out + (size_t)5 * N + (size_t)base * 25);
            float4* gk4 = (float4*)(out + (size_t)30 * N + (size_t)base * 10);
            const float4* lx4 = (const float4*)(obuf + OB_X);
            const float4* lp4 = (const float4*)(obuf + OB_P);
            const float4* lk4 = (const float4*)(obuf + OB_K);
            gx4[tid] = lx4[tid];
            if (tid < 16) gx4[64 + tid] = lx4[64 + tid];
            #pragma unroll
            for (int j = 0; j < 6; ++j) gp4[j * 64 + tid] = lp4[j * 64 + tid];
            if (tid < 16) gp4[384 + tid] = lp4[384 + tid];
            #pragma unroll
            for (int j = 0; j < 2; ++j) gk4[j * 64 + tid] = lk4[j * 64 + tid];
            if (tid < 32) gk4[128 + tid] = lk4[128 + tid];
        } else {
            // Tail tile (global last, valid < 64): direct guarded path.
            if (i < N) {
                const float* pr = Pg + (size_t)i * 25;
                EkfOut o = ekf_math(xg[i * 5 + 0], xg[i * 5 + 1], xg[i * 5 + 2],
                                    ag[i * 2 + 0], ag[i * 2 + 1],
                                    Yg[i], Yg[N + i],
                                    pr[0], pr[1], pr[2], pr[5], pr[6], pr[7],
                                    pr[10], pr[11], pr[12],
                                    g0, g1, og0, og1, q0, q1, q2, q3, q4,
                                    e2s0, e2s1, e2k0, e2k1);
                float* gx = out + (size_t)i * 5;
                gx[0] = o.px; gx[1] = o.py; gx[2] = o.ang; gx[3] = o.xn3; gx[4] = o.xn4;
                float* gp = out + (size_t)5 * N + (size_t)i * 25;
                gp[0] = o.t00; gp[1] = o.s01; gp[2] = o.s02; gp[3] = 0.f; gp[4] = 0.f;
                gp[5] = o.s01; gp[6] = o.t11; gp[7] = o.s12; gp[8] = 0.f; gp[9] = 0.f;
                gp[10] = o.s02; gp[11] = o.s12; gp[12] = o.t22; gp[13] = 0.f; gp[14] = 0.f;
                gp[15] = 0.f; gp[16] = 0.f; gp[17] = 0.f; gp[18] = o.Pn33; gp[19] = 0.f;
                gp[20] = 0.f; gp[21] = 0.f; gp[22] = 0.f; gp[23] = 0.f; gp[24] = o.Pn44;
                float* gk = out + (size_t)30 * N + (size_t)i * 10;
                gk[0] = 0.f; gk[1] = 0.f; gk[2] = 0.f; gk[3] = 0.f; gk[4] = 0.f;
                gk[5] = 0.f; gk[6] = o.K30; gk[7] = 0.f; gk[8] = 0.f; gk[9] = o.K41;
            }
        }
    };

    // Ping-pong over two named register tiles (no runtime-indexed arrays).
    while (true) {
        process(A, B);
        if (++k >= myTiles) break;
        process(B, A);
        if (++k >= myTiles) break;
    }
}

extern "C" void kernel_launch(void* const* d_in, const int* in_sizes, int n_in,
                              void* d_out, int out_size, void* d_ws, size_t ws_size,
                              hipStream_t stream) {
    const float* x     = (const float*)d_in[0];
    const float* P     = (const float*)d_in[1];
    const float* a     = (const float*)d_in[2];
    const float* Y     = (const float*)d_in[3];
    const float* n1    = (const float*)d_in[4];
    const float* n2s   = (const float*)d_in[5];
    const float* n2k   = (const float*)d_in[6];
    const float* gains = (const float*)d_in[7];
    const float* og    = (const float*)d_in[8];
    const int N = in_sizes[0] / 5;
    const int tiles = (N + BLK - 1) / BLK;
    int G = 2560;                    // 10 blocks/CU x 256 CUs, ~3 tiles/block
    if (G > tiles) G = tiles;
    ekf_kernel<<<G, BLK, 0, stream>>>(x, P, a, Y, n1, n2s, n2k, gains, og,
                                      (float*)d_out, N);
}